// Round 3
// baseline (422.772 us; speedup 1.0000x reference)
//
#include <hip/hip_runtime.h>

typedef unsigned short u16;
typedef __attribute__((ext_vector_type(8))) short bf16x8;
typedef __attribute__((ext_vector_type(4))) float f32x4;

struct __align__(8) u16x4_t { u16 x, y, z, w; };

__device__ __forceinline__ float b2f(u16 b) {
  union { unsigned u; float f; } v; v.u = ((unsigned)b) << 16; return v.f;
}
__device__ __forceinline__ u16 f2b(float f) {
  union { float f; unsigned u; } v; v.f = f;
  unsigned r = v.u + 0x7fffu + ((v.u >> 16) & 1u);
  return (u16)(r >> 16);
}

// ---------------- mask + unique main list ----------------
__global__ void set_mask_append(const int* __restrict__ main_idx, int* __restrict__ mask,
                                int* __restrict__ mlist, int* __restrict__ cpos,
                                int* __restrict__ mcount, int n) {
  int t = blockIdx.x * 256 + threadIdx.x;
  if (t >= n) return;
  int o = main_idx[t];
  if (atomicCAS(&mask[o], 0, 1) == 0) {
    int i = atomicAdd(mcount, 1);
    mlist[i] = o;
    cpos[o] = i;
  }
}

// ---------------- weights fp32 -> bf16, all three in one launch ----------------
// layout in wb (u16 units): Wp [0,65536) Wi [65536,262144) Wh [262144,458752)
__global__ void cvt_weights(const float* __restrict__ Wp, const float* __restrict__ Wi,
                            const float* __restrict__ Wh, u16* __restrict__ wb) {
  int t = blockIdx.x * 256 + threadIdx.x;  // [0, 114688) float4 slots
  const float* src; int o;
  if (t < 16384)      { src = Wp; o = t; }
  else if (t < 65536) { src = Wi; o = t - 16384; }
  else                { src = Wh; o = t - 65536; }
  float4 v = ((const float4*)src)[o];
  u16x4_t q;
  q.x = f2b(v.x); q.y = f2b(v.y); q.z = f2b(v.z); q.w = f2b(v.w);
  ((u16x4_t*)wb)[t] = q;
}

// ---------------- masked CSR build ----------------
__global__ void count_edges(const int* __restrict__ obj_idx, const int* __restrict__ mask,
                            int* __restrict__ deg, int n) {
  int e = blockIdx.x * 256 + threadIdx.x;
  if (e >= n) return;
  int o = obj_idx[e];
  if (mask[o]) atomicAdd(&deg[o], 1);
}

__global__ void scan_block(const int* __restrict__ deg, int* __restrict__ offs,
                           int* __restrict__ bsum, int n) {
  __shared__ int tmp[256];
  int t = threadIdx.x;
  int i = blockIdx.x * 256 + t;
  int v = (i < n) ? deg[i] : 0;
  tmp[t] = v;
  __syncthreads();
  for (int off = 1; off < 256; off <<= 1) {
    int x = (t >= off) ? tmp[t - off] : 0;
    __syncthreads();
    tmp[t] += x;
    __syncthreads();
  }
  if (i < n) offs[i] = tmp[t] - v;
  if (t == 255) bsum[blockIdx.x] = tmp[255];
}

__global__ void scan_tops(int* __restrict__ bsum, int nb) {
  __shared__ int tmp[256];
  int t = threadIdx.x;
  int v = (t < nb) ? bsum[t] : 0;
  tmp[t] = v;
  __syncthreads();
  for (int off = 1; off < 256; off <<= 1) {
    int x = (t >= off) ? tmp[t - off] : 0;
    __syncthreads();
    tmp[t] += x;
    __syncthreads();
  }
  if (t < nb) bsum[t] = tmp[t] - v;
}

// scan finalize + rrows build (rrows grid fits inside n-grid: Mpad < n)
__global__ void scan_add_rrows(int* __restrict__ offs, const int* __restrict__ bsum,
                               const int* __restrict__ mlist, const int* __restrict__ mcount,
                               int* __restrict__ rrows, int n, int Mpad) {
  int i = blockIdx.x * 256 + threadIdx.x;
  if (i < n) offs[i] += bsum[blockIdx.x];
  if (i < Mpad) {
    int mc = *mcount;
    rrows[i] = (i < mc) ? mlist[i] : 0;
  }
}

__global__ void fill_edges(const int* __restrict__ obj_idx, const int* __restrict__ evt_idx,
                           const int* __restrict__ mask, const int* __restrict__ offs,
                           int* __restrict__ cursor, int* __restrict__ elist, int n) {
  int e = blockIdx.x * 256 + threadIdx.x;
  if (e >= n) return;
  int o = obj_idx[e];
  if (!mask[o]) return;
  int pos = atomicAdd(&cursor[o], 1);
  elist[offs[o] + pos] = evt_idx[e];
}

// ---------------- register-accumulated scatter-mean, compacted output ----------------
__global__ __launch_bounds__(256)
void accum_prof(const u16* __restrict__ P, const int* __restrict__ elist,
                const int* __restrict__ offs, const int* __restrict__ deg,
                const int* __restrict__ mlist, const int* __restrict__ mcount,
                u16* __restrict__ prof, int Mpad) {
  const int wave = threadIdx.x >> 6;
  const int lane = threadIdx.x & 63;
  const int i = blockIdx.x * 4 + wave;
  if (i >= Mpad) return;
  const int mc = *mcount;
  float a0 = 0.f, a1 = 0.f, a2 = 0.f, a3 = 0.f;
  int d = 0;
  if (i < mc) {
    const int o = mlist[i];
    const int off = offs[o];
    d = deg[o];
    int j = 0;
    for (; j + 1 < d; j += 2) {
      int e0 = elist[off + j], e1 = elist[off + j + 1];
      u16x4_t p0 = *(const u16x4_t*)(P + (size_t)e0 * 256 + lane * 4);
      u16x4_t p1 = *(const u16x4_t*)(P + (size_t)e1 * 256 + lane * 4);
      a0 += b2f(p0.x) + b2f(p1.x);
      a1 += b2f(p0.y) + b2f(p1.y);
      a2 += b2f(p0.z) + b2f(p1.z);
      a3 += b2f(p0.w) + b2f(p1.w);
    }
    if (j < d) {
      int e0 = elist[off + j];
      u16x4_t p0 = *(const u16x4_t*)(P + (size_t)e0 * 256 + lane * 4);
      a0 += b2f(p0.x); a1 += b2f(p0.y); a2 += b2f(p0.z); a3 += b2f(p0.w);
    }
  }
  float s = 1.f / fmaxf((float)d, 1.f);
  u16x4_t ov;
  ov.x = f2b(a0 * s); ov.y = f2b(a1 * s); ov.z = f2b(a2 * s); ov.w = f2b(a3 * s);
  *(u16x4_t*)(prof + (size_t)i * 256 + lane * 4) = ov;
}

// ---------------- bf16 MFMA GEMM: C[M,N] = A[M,K] @ B[N,K]^T + bias ----------------
// CVT=1: A is fp32, converted in-register during staging. GATHER=1: row = ridx[m].
template<int RELU, int GATHER, int CVT>
__global__ __launch_bounds__(256, 2)
void gemm_bt(const u16* __restrict__ Ab, const float* __restrict__ Af,
             const u16* __restrict__ B, const float* __restrict__ bias,
             u16* __restrict__ C, const int* __restrict__ ridx,
             int M, int N, int K) {
  __shared__ u16 lA[128 * 64];
  __shared__ u16 lB[128 * 64];
  const int tid  = threadIdx.x;
  const int lane = tid & 63;
  const int wave = tid >> 6;
  const int m0 = blockIdx.x * 128;
  const int n0 = blockIdx.y * 128;

  f32x4 acc[4][4] = {};
  const int mR = (wave & 1) * 64;
  const int nC = (wave >> 1) * 64;

  // per-thread staging coordinates, constant across the K loop
  int arow[4], brow[4], kkv[4];
#pragma unroll
  for (int s = 0; s < 4; ++s) {
    int slot = s * 256 + tid;
    int row  = slot >> 3;
    kkv[s]   = (slot & 7) * 8;
    int ar;
    if (GATHER) ar = ridx[m0 + row];
    else { ar = m0 + row; ar = (ar < M) ? ar : (M - 1); }
    arow[s] = ar;
    brow[s] = n0 + row;
  }

  for (int kt = 0; kt < K; kt += 64) {
    __syncthreads();
    float4 va[4][2];
#pragma unroll
    for (int s = 0; s < 4; ++s) {
      int slot = s * 256 + tid;
      const u16* gB = B + (size_t)brow[s] * K + (kt + kkv[s]);
      __builtin_amdgcn_global_load_lds(
          (const __attribute__((address_space(1))) void*)gB,
          (__attribute__((address_space(3))) void*)(lB + s * 2048 + wave * 512),
          16, 0, 0);
      if (CVT) {
        const float* gA = Af + (size_t)arow[s] * K + (kt + kkv[s]);
        va[s][0] = *(const float4*)gA;
        va[s][1] = *(const float4*)(gA + 4);
      } else {
        const u16* gA = Ab + (size_t)arow[s] * K + (kt + kkv[s]);
        __builtin_amdgcn_global_load_lds(
            (const __attribute__((address_space(1))) void*)gA,
            (__attribute__((address_space(3))) void*)(lA + s * 2048 + wave * 512),
            16, 0, 0);
      }
      (void)slot;
    }
    if (CVT) {
#pragma unroll
      for (int s = 0; s < 4; ++s) {
        int slot = s * 256 + tid;
        bf16x8 w;
        w[0] = (short)f2b(va[s][0].x); w[1] = (short)f2b(va[s][0].y);
        w[2] = (short)f2b(va[s][0].z); w[3] = (short)f2b(va[s][0].w);
        w[4] = (short)f2b(va[s][1].x); w[5] = (short)f2b(va[s][1].y);
        w[6] = (short)f2b(va[s][1].z); w[7] = (short)f2b(va[s][1].w);
        *(bf16x8*)(lA + slot * 8) = w;
      }
    }
    __syncthreads();

#pragma unroll
    for (int ks = 0; ks < 2; ++ks) {
      const int kb = ks * 32 + (lane >> 4) * 8;
      bf16x8 af[4], bfr[4];
#pragma unroll
      for (int i = 0; i < 4; ++i) {
        af[i]  = *(const bf16x8*)(lA + (mR + i * 16 + (lane & 15)) * 64 + kb);
        bfr[i] = *(const bf16x8*)(lB + (nC + i * 16 + (lane & 15)) * 64 + kb);
      }
#pragma unroll
      for (int i = 0; i < 4; ++i)
#pragma unroll
        for (int j = 0; j < 4; ++j)
          acc[i][j] = __builtin_amdgcn_mfma_f32_16x16x32_bf16(af[i], bfr[j], acc[i][j], 0, 0, 0);
    }
  }

  // C/D layout: col=lane&15, row=(lane>>4)*4+reg (verified m89/m91)
  const int crow = (lane >> 4) * 4;
  const int ccol = lane & 15;
#pragma unroll
  for (int i = 0; i < 4; ++i) {
#pragma unroll
    for (int j = 0; j < 4; ++j) {
      int col = n0 + nC + j * 16 + ccol;
      float bv = bias[col];
#pragma unroll
      for (int q = 0; q < 4; ++q) {
        int row = m0 + mR + i * 16 + crow + q;
        if (row < M) {
          float v = acc[i][j][q] + bv;
          if (RELU) v = fmaxf(v, 0.f);
          C[(size_t)row * N + col] = f2b(v);
        }
      }
    }
  }
}

// ---------------- GRU gates + masked blend (compact gi/gh via cpos) ----------------
__global__ __launch_bounds__(256)
void gate_out(const u16* __restrict__ gi, const u16* __restrict__ gh,
              const float* __restrict__ objX, const int* __restrict__ mask,
              const int* __restrict__ cpos, float* __restrict__ out, int nObj) {
  const int row = blockIdx.x;
  const int d = threadIdx.x;
  const size_t o256 = (size_t)row * 256 + d;
  float x = objX[o256];
  float res = x;
  if (mask[row]) {
    const size_t c768 = (size_t)cpos[row] * 768 + d;
    float ir = b2f(gi[c768]), iz = b2f(gi[c768 + 256]), inn = b2f(gi[c768 + 512]);
    float hr = b2f(gh[c768]), hz = b2f(gh[c768 + 256]), hn = b2f(gh[c768 + 512]);
    float r = 1.f / (1.f + __expf(-(ir + hr)));
    float z = 1.f / (1.f + __expf(-(iz + hz)));
    float a = inn + r * hn;
    float n = 1.f - 2.f / (__expf(2.f * a) + 1.f);
    res = (1.f - z) * n + z * x;
  }
  out[o256] = res;
}

// ---------------- workspace layout (bytes) ----------------
//          0  P      51,200,000  (dead after accum)  -> gi reuse (38,535,168)
// 51,200,000  gh     38,535,168
// 89,735,168  prof   12,845,056  (25088 x 256 bf16 compact)
// 102,580,224 wb        917,504  (wpb|wib|whb bf16, contiguous)
// 103,497,728 deg       200,000  \
// 103,697,728 offs      200,000   |
// 103,897,728 cursor    200,000   | one memset zeroes
// 104,097,728 mask      200,000   | [103,497,728 .. 104,699,520)
// 104,297,728 cpos      200,000   |
// 104,497,728 mlist     100,352   |
// 104,598,080 rrows     100,352   | (overwritten anyway)
// 104,698,432 bsum        1,024   |
// 104,699,456 mcount         64  /
// 104,699,520 elist   2,000,000
// total 106,699,520

extern "C" void kernel_launch(void* const* d_in, const int* in_sizes, int n_in,
                              void* d_out, int out_size, void* d_ws, size_t ws_size,
                              hipStream_t stream) {
  const float* objX   = (const float*)d_in[0];
  const float* evtX   = (const float*)d_in[1];
  const int* obj_idx  = (const int*)d_in[2];
  const int* evt_idx  = (const int*)d_in[3];
  const int* main_idx = (const int*)d_in[4];
  const float* Wp = (const float*)d_in[5];
  const float* bp = (const float*)d_in[6];
  const float* Wi = (const float*)d_in[7];
  const float* bi = (const float*)d_in[8];
  const float* Wh = (const float*)d_in[9];
  const float* bh = (const float*)d_in[10];

  const int nObj  = in_sizes[0] / 256;   // 50000
  const int nEvt  = in_sizes[1] / 256;   // 100000
  const int nEdge = in_sizes[2];         // 500000
  const int nMain = in_sizes[4];         // 25000
  const int Mpad  = ((nMain + 127) / 128) * 128;  // 25088

  char* ws = (char*)d_ws;
  u16*   P     = (u16*)(ws + 0);
  u16*   gi    = (u16*)(ws + 0);
  u16*   gh    = (u16*)(ws + 51200000);
  u16*   prof  = (u16*)(ws + 89735168);
  u16*   wb    = (u16*)(ws + 102580224);
  u16*   wpb   = wb;
  u16*   wib   = wb + 65536;
  u16*   whb   = wb + 262144;
  int*   deg   = (int*)(ws + 103497728);
  int*   offs  = (int*)(ws + 103697728);
  int*   cursor= (int*)(ws + 103897728);
  int*   mask  = (int*)(ws + 104097728);
  int*   cpos  = (int*)(ws + 104297728);
  int*   mlist = (int*)(ws + 104497728);
  int*   rrows = (int*)(ws + 104598080);
  int*   bsum  = (int*)(ws + 104698432);
  int*   mcount= (int*)(ws + 104699456);
  int*   elist = (int*)(ws + 104699520);
  float* out   = (float*)d_out;

  hipMemsetAsync(ws + 103497728, 0, 1201792, stream);

  set_mask_append<<<(nMain + 255) / 256, 256, 0, stream>>>(main_idx, mask, mlist, cpos, mcount, nMain);
  cvt_weights<<<448, 256, 0, stream>>>(Wp, Wi, Wh, wb);

  // P = relu(evtX_fp32 @ Wp^T + bp)   [100000 x 256], A converted in-kernel
  gemm_bt<1, 0, 1><<<dim3((nEvt + 127) / 128, 2), 256, 0, stream>>>(
      nullptr, evtX, wpb, bp, P, nullptr, nEvt, 256, 256);

  // masked CSR
  count_edges<<<(nEdge + 255) / 256, 256, 0, stream>>>(obj_idx, mask, deg, nEdge);
  scan_block<<<(nObj + 255) / 256, 256, 0, stream>>>(deg, offs, bsum, nObj);
  scan_tops<<<1, 256, 0, stream>>>(bsum, (nObj + 255) / 256);
  scan_add_rrows<<<(nObj + 255) / 256, 256, 0, stream>>>(offs, bsum, mlist, mcount, rrows, nObj, Mpad);
  fill_edges<<<(nEdge + 255) / 256, 256, 0, stream>>>(obj_idx, evt_idx, mask, offs, cursor, elist, nEdge);

  // register scatter-mean -> compact bf16 profile
  accum_prof<<<(Mpad + 3) / 4, 256, 0, stream>>>(P, elist, offs, deg, mlist, mcount, prof, Mpad);

  // compact GRU GEMMs [25088 x 768]
  gemm_bt<0, 0, 0><<<dim3(Mpad / 128, 6), 256, 0, stream>>>(
      prof, nullptr, wib, bi, gi, nullptr, Mpad, 768, 256);
  gemm_bt<0, 1, 1><<<dim3(Mpad / 128, 6), 256, 0, stream>>>(
      nullptr, objX, whb, bh, gh, rrows, Mpad, 768, 256);

  // gates + masked blend
  gate_out<<<nObj, 256, 0, stream>>>(gi, gh, objX, mask, cpos, out, nObj);
}